// Round 8
// baseline (492.316 us; speedup 1.0000x reference)
//
#include <hip/hip_runtime.h>
#include <hip/hip_bf16.h>

// Problem constants
#define NROWS 16384      // B*C = 32*512
#define DDIM  256        // H*W
#define KEMB  8192
#define DECAYF 0.99f
#define ONE_MINUS_DECAY 0.01f
#define EPSF 1e-5f

// Output layout (all float32, concatenated in return order)
#define O_QST   0
#define O_LOSS  4194304
#define O_IDX   4194305
#define O_EMB   4210689
#define O_ECS   6307841
#define O_EES   6316033

typedef __attribute__((ext_vector_type(8))) short short8;
typedef __attribute__((ext_vector_type(4))) float f32x4;

// fp32 -> bf16 (RNE) as raw ushort, and back
static __device__ __forceinline__ unsigned short f2bf(float x) {
    unsigned int u = __float_as_uint(x);
    return (unsigned short)((u + 0x7fffu + ((u >> 16) & 1u)) >> 16);
}
static __device__ __forceinline__ float bf2f(unsigned short h) {
    return __uint_as_float(((unsigned int)h) << 16);
}

// async global->LDS, 16B per lane; lds base wave-uniform, lane i lands at +16*i
static __device__ __forceinline__ void gload16(const unsigned short* g, unsigned short* l) {
    __builtin_amdgcn_global_load_lds(
        (const __attribute__((address_space(1))) unsigned int*)g,
        (__attribute__((address_space(3))) unsigned int*)l, 16, 0, 0);
}

// ---------------- prep_e: one wave per code k ----------------
// e-norm (fp32 exact) + e hi/lo bf16 split + block-partial 0.99*sum(ecs)
// into scal[1] (scal pre-zeroed by memset). ecs/ees outputs now written by
// code_update, not here.
__global__ __launch_bounds__(256) void prep_e(const float* __restrict__ emb,
                                              const float* __restrict__ ecs_in,
                                              float* __restrict__ enorm,
                                              unsigned short* __restrict__ eh,
                                              unsigned short* __restrict__ el,
                                              float* __restrict__ scal) {
    const int w = threadIdx.x >> 6;
    const int k = blockIdx.x * 4 + w;
    const int lane = threadIdx.x & 63;
    const int base = k * DDIM + lane * 4;
    const float4 v = *(const float4*)&emb[base];
    ushort4 h, l;
    {
        const float* vp = (const float*)&v;
        unsigned short hh;
        hh = f2bf(vp[0]); h.x = hh; l.x = f2bf(vp[0] - bf2f(hh));
        hh = f2bf(vp[1]); h.y = hh; l.y = f2bf(vp[1] - bf2f(hh));
        hh = f2bf(vp[2]); h.z = hh; l.z = f2bf(vp[2] - bf2f(hh));
        hh = f2bf(vp[3]); h.w = hh; l.w = f2bf(vp[3] - bf2f(hh));
    }
    *(ushort4*)&eh[base] = h;
    *(ushort4*)&el[base] = l;
    float sum = v.x * v.x + v.y * v.y + v.z * v.z + v.w * v.w;
    for (int o = 32; o; o >>= 1) sum += __shfl_down(sum, o);
    __shared__ float sc[4];
    if (lane == 0) {
        enorm[k] = sum;
        sc[w] = DECAYF * ecs_in[k];
    }
    __syncthreads();
    if (threadIdx.x == 0) atomicAdd(&scal[1], sc[0] + sc[1] + sc[2] + sc[3]);
}

// ---------------- prep_z: one wave per row ----------------
__global__ __launch_bounds__(256) void prep_z(const float* __restrict__ z,
                                              unsigned short* __restrict__ zh,
                                              unsigned short* __restrict__ zl,
                                              unsigned long long* __restrict__ key64) {
    const int n = blockIdx.x * 4 + (threadIdx.x >> 6);
    const int lane = threadIdx.x & 63;
    const int base = n * DDIM + lane * 4;
    const float4 v = *(const float4*)&z[base];
    ushort4 h, l;
    {
        const float* vp = (const float*)&v;
        unsigned short hh;
        hh = f2bf(vp[0]); h.x = hh; l.x = f2bf(vp[0] - bf2f(hh));
        hh = f2bf(vp[1]); h.y = hh; l.y = f2bf(vp[1] - bf2f(hh));
        hh = f2bf(vp[2]); h.z = hh; l.z = f2bf(vp[2] - bf2f(hh));
        hh = f2bf(vp[3]); h.w = hh; l.w = f2bf(vp[3] - bf2f(hh));
    }
    *(ushort4*)&zh[base] = h;
    *(ushort4*)&zl[base] = l;
    if (lane == 0) key64[n] = ~0ull;
}

// ---------------- argmin_mfma: bf16x3 MFMA GEMM + fused argmin (R7-exact) ---
// Block 128x128, 4 waves (2x2 of 64x64), BK=32, pre-split bf16 inputs,
// global_load_lds width=16 staging. Proven 293us / MfmaUtil 31% config —
// LDS-read-throughput-bound plateau for this structure (R4/R5/R6 variants
// all regressed).
__global__ __launch_bounds__(256) void argmin_mfma(const unsigned short* __restrict__ zh,
                                                   const unsigned short* __restrict__ zl,
                                                   const unsigned short* __restrict__ eh,
                                                   const unsigned short* __restrict__ el,
                                                   const float* __restrict__ enorm,
                                                   unsigned long long* __restrict__ key64) {
    __shared__ unsigned short Ah[128][32];
    __shared__ unsigned short Al[128][32];
    __shared__ unsigned short Bh[128][32];
    __shared__ unsigned short Bl[128][32];

    const int tid = threadIdx.x;
    const int lane = tid & 63;
    const int wid = tid >> 6;
    const int wm = wid >> 1, wn = wid & 1;
    const int tx = lane & 15, quad = lane >> 4;

    const int row0 = blockIdx.x * 128;
    const int col0 = blockIdx.y * 128;

    const int w32 = wid * 32;
    const int r16 = lane >> 2;
    const int c8 = (lane & 3) * 8;

    f32x4 acc[4][4];
#pragma unroll
    for (int i = 0; i < 4; i++)
#pragma unroll
        for (int j = 0; j < 4; j++) acc[i][j] = (f32x4){0.f, 0.f, 0.f, 0.f};

    for (int dstep = 0; dstep < DDIM; dstep += 32) {
        __syncthreads();
#pragma unroll
        for (int i = 0; i < 2; i++) {
            const int lr = w32 + i * 16;
            const size_t ga = (size_t)(row0 + lr + r16) * DDIM + dstep + c8;
            const size_t gb = (size_t)(col0 + lr + r16) * DDIM + dstep + c8;
            gload16(&zh[ga], &Ah[lr][0]);
            gload16(&zl[ga], &Al[lr][0]);
            gload16(&eh[gb], &Bh[lr][0]);
            gload16(&el[gb], &Bl[lr][0]);
        }
        __syncthreads();

        short8 aH[4], aL[4], bH[4], bL[4];
        const int ar = wm * 64 + tx;
        const int br = wn * 64 + tx;
#pragma unroll
        for (int mi = 0; mi < 4; mi++) {
            aH[mi] = *(const short8*)&Ah[ar + mi * 16][quad * 8];
            aL[mi] = *(const short8*)&Al[ar + mi * 16][quad * 8];
        }
#pragma unroll
        for (int nj = 0; nj < 4; nj++) {
            bH[nj] = *(const short8*)&Bh[br + nj * 16][quad * 8];
            bL[nj] = *(const short8*)&Bl[br + nj * 16][quad * 8];
        }
#pragma unroll
        for (int mi = 0; mi < 4; mi++)
#pragma unroll
            for (int nj = 0; nj < 4; nj++) {
                acc[mi][nj] = __builtin_amdgcn_mfma_f32_16x16x32_bf16(aH[mi], bH[nj], acc[mi][nj], 0, 0, 0);
                acc[mi][nj] = __builtin_amdgcn_mfma_f32_16x16x32_bf16(aL[mi], bH[nj], acc[mi][nj], 0, 0, 0);
                acc[mi][nj] = __builtin_amdgcn_mfma_f32_16x16x32_bf16(aH[mi], bL[nj], acc[mi][nj], 0, 0, 0);
            }
    }

    float en[4];
    int colv[4];
#pragma unroll
    for (int nj = 0; nj < 4; nj++) {
        colv[nj] = col0 + wn * 64 + nj * 16 + tx;
        en[nj] = enorm[colv[nj]];
    }
#pragma unroll
    for (int mi = 0; mi < 4; mi++) {
#pragma unroll
        for (int r = 0; r < 4; r++) {
            unsigned long long best = ~0ull;
#pragma unroll
            for (int nj = 0; nj < 4; nj++) {
                float d = en[nj] - 2.0f * acc[mi][nj][r];
                unsigned int db = __float_as_uint(d);
                db = (db & 0x80000000u) ? ~db : (db | 0x80000000u);
                unsigned long long key = ((unsigned long long)db << 32) | (unsigned int)colv[nj];
                if (key < best) best = key;
            }
#pragma unroll
            for (int m = 1; m < 16; m <<= 1) {
                unsigned long long o = __shfl_xor(best, m);
                if (o < best) best = o;
            }
            if (tx == 0)
                atomicMin(&key64[row0 + wm * 64 + mi * 16 + quad * 4 + r], best);
        }
    }
}

// ---------------- quant_row: qst + idx + loss + histogram ----------------
__global__ __launch_bounds__(256) void quant_row(const float* __restrict__ z,
                                                 const float* __restrict__ emb,
                                                 const unsigned long long* __restrict__ key64,
                                                 float* __restrict__ o_qst,
                                                 float* __restrict__ o_idx,
                                                 int* __restrict__ cnt,
                                                 float* __restrict__ scal) {
    const int w = threadIdx.x >> 6;
    const int lane = threadIdx.x & 63;
    const int nbase = blockIdx.x * 16 + w * 4;
    const int d0 = lane * 4;
    float ploc = 0.f;
#pragma unroll
    for (int r = 0; r < 4; r++) {
        const int n = nbase + r;
        const int k = (int)(key64[n] & 0xFFFFFFFFull);
        const float4 zv = *(const float4*)&z[n * DDIM + d0];
        const float4 ev = *(const float4*)&emb[k * DDIM + d0];
        const float dx = ev.x - zv.x, dy = ev.y - zv.y, dz2 = ev.z - zv.z, dw = ev.w - zv.w;
        float4 q;
        q.x = zv.x + dx; q.y = zv.y + dy; q.z = zv.z + dz2; q.w = zv.w + dw;
        *(float4*)&o_qst[n * DDIM + d0] = q;
        ploc += dx * dx + dy * dy + dz2 * dz2 + dw * dw;
        if (lane == 0) {
            o_idx[n] = (float)k;
            atomicAdd(&cnt[k], 1);
        }
    }
    for (int o = 32; o; o >>= 1) ploc += __shfl_down(ploc, o);
    __shared__ float sh[4];
    if (lane == 0) sh[w] = ploc;
    __syncthreads();
    if (threadIdx.x == 0) atomicAdd(&scal[0], sh[0] + sh[1] + sh[2] + sh[3]);
}

// ---------------- scan: exclusive prefix sum of cnt[8192] -> basep ----------
__global__ __launch_bounds__(256) void scan_kernel(const int* __restrict__ cnt,
                                                   int* __restrict__ basep) {
    const int t = threadIdx.x;
    int loc[32];
    int run = 0;
#pragma unroll
    for (int i = 0; i < 32; i++) {
        loc[i] = run;
        run += cnt[t * 32 + i];
    }
    __shared__ int a[256], b[256];
    a[t] = run;
    __syncthreads();
    int* src = a;
    int* dst = b;
    for (int off = 1; off < 256; off <<= 1) {
        dst[t] = (t >= off) ? (src[t] + src[t - off]) : src[t];
        __syncthreads();
        int* tmp = src; src = dst; dst = tmp;
    }
    const int excl = (t == 0) ? 0 : src[t - 1];
#pragma unroll
    for (int i = 0; i < 32; i++) basep[t * 32 + i] = excl + loc[i];
}

// ---------------- scatter: invert idx -> per-code row buckets ----------------
__global__ __launch_bounds__(256) void scatter_kernel(const unsigned long long* __restrict__ key64,
                                                      const int* __restrict__ basep,
                                                      int* __restrict__ cur,
                                                      int* __restrict__ rowlist) {
    const int n = blockIdx.x * 256 + threadIdx.x;
    const int k = (int)(key64[n] & 0xFFFFFFFFull);
    const int slot = basep[k] + atomicAdd(&cur[k], 1);
    rowlist[slot] = n;
}

// ---------------- code_update: one wave per code ----------------
// new_ecs = 0.99*ecs + 0.01*n (exact);  new_ees = 0.99*ees + 0.01*sum(z rows);
// new_embedding = new_ees / smoothed.  Fuses the old finalize kernel.
__global__ __launch_bounds__(256) void code_update(const float* __restrict__ z,
                                                   const float* __restrict__ ecs_in,
                                                   const float* __restrict__ ees_in,
                                                   const int* __restrict__ cnt,
                                                   const int* __restrict__ basep,
                                                   const int* __restrict__ rowlist,
                                                   const float* __restrict__ scal,
                                                   float* __restrict__ o_ecs,
                                                   float* __restrict__ o_ees,
                                                   float* __restrict__ o_emb,
                                                   float* __restrict__ o_loss) {
    const int w = threadIdx.x >> 6;
    const int lane = threadIdx.x & 63;
    const int k = blockIdx.x * 4 + w;
    const int c = cnt[k];
    const int b = basep[k];
    const int d0 = lane * 4;
    float4 sum = {0.f, 0.f, 0.f, 0.f};
    for (int i = 0; i < c; ++i) {
        const int row = rowlist[b + i];
        const float4 zv = *(const float4*)&z[row * DDIM + d0];
        sum.x += zv.x; sum.y += zv.y; sum.z += zv.z; sum.w += zv.w;
    }
    const float4 e0 = *(const float4*)&ees_in[k * DDIM + d0];
    float4 ne;
    ne.x = DECAYF * e0.x + ONE_MINUS_DECAY * sum.x;
    ne.y = DECAYF * e0.y + ONE_MINUS_DECAY * sum.y;
    ne.z = DECAYF * e0.z + ONE_MINUS_DECAY * sum.z;
    ne.w = DECAYF * e0.w + ONE_MINUS_DECAY * sum.w;
    *(float4*)&o_ees[k * DDIM + d0] = ne;
    const float ntot = scal[1] + ONE_MINUS_DECAY * (float)NROWS;
    const float necs = DECAYF * ecs_in[k] + ONE_MINUS_DECAY * (float)c;
    const float sm = (necs + EPSF) / (ntot + (float)KEMB * EPSF) * ntot;
    const float inv = 1.0f / sm;
    float4 oe;
    oe.x = ne.x * inv; oe.y = ne.y * inv; oe.z = ne.z * inv; oe.w = ne.w * inv;
    *(float4*)&o_emb[k * DDIM + d0] = oe;
    if (lane == 0) o_ecs[k] = necs;
    if (k == 0 && threadIdx.x == 0)
        o_loss[0] = 0.25f * scal[0] / (float)(NROWS * DDIM);
}

extern "C" void kernel_launch(void* const* d_in, const int* in_sizes, int n_in,
                              void* d_out, int out_size, void* d_ws, size_t ws_size,
                              hipStream_t stream) {
    const float* z   = (const float*)d_in[0];
    const float* emb = (const float*)d_in[1];
    const float* ecs = (const float*)d_in[2];
    const float* ees = (const float*)d_in[3];

    float* out = (float*)d_out;
    char*  ws  = (char*)d_ws;

    // ws small-scratch layout (bytes):
    float* enorm = (float*)ws;                                    // 0      : 32 KB
    unsigned long long* key64 = (unsigned long long*)(ws + 32768);// 32768  : 128 KB
    float* scal  = (float*)(ws + 163840);                         // 163840 : 256 B (zeroed)
    int*   cnt   = (int*)(ws + 164096);                           // 164096 : 32 KB (zeroed)
    int*   cur   = (int*)(ws + 196864);                           // 196864 : 32 KB (zeroed)
    int*   basep = (int*)(ws + 229632);                           // 229632 : 32 KB
    int*   rowlist = (int*)(ws + 262400);                         // 262400 : 64 KB

    // bf16 hi/lo scratch: prefer d_ws if large enough, else alias output
    // regions overwritten later (zh/zl in O_QST, eh/el in O_EMB).
    const size_t big0 = 327936;
    const size_t bigbytes = (size_t)(NROWS + KEMB) * DDIM * 2 * 2;// 24 MB
    unsigned short *zh, *zl, *ehp, *elp;
    if (ws_size >= big0 + bigbytes) {
        zh  = (unsigned short*)(ws + big0);
        zl  = zh + NROWS * DDIM;
        ehp = zl + NROWS * DDIM;
        elp = ehp + KEMB * DDIM;
    } else {
        zh  = (unsigned short*)(out + O_QST);
        zl  = zh + NROWS * DDIM;
        ehp = (unsigned short*)(out + O_EMB);
        elp = ehp + KEMB * DDIM;
    }

    // zero scal + cnt + cur in one shot (contiguous 163840..262400)
    hipMemsetAsync(ws + 163840, 0, 262400 - 163840, stream);
    prep_e<<<KEMB / 4, 256, 0, stream>>>(emb, ecs, enorm, ehp, elp, scal);
    prep_z<<<NROWS / 4, 256, 0, stream>>>(z, zh, zl, key64);
    argmin_mfma<<<dim3(NROWS / 128, KEMB / 128), 256, 0, stream>>>(zh, zl, ehp, elp, enorm, key64);
    quant_row<<<NROWS / 16, 256, 0, stream>>>(z, emb, key64, out + O_QST, out + O_IDX, cnt, scal);
    scan_kernel<<<1, 256, 0, stream>>>(cnt, basep);
    scatter_kernel<<<NROWS / 256, 256, 0, stream>>>(key64, basep, cur, rowlist);
    code_update<<<KEMB / 4, 256, 0, stream>>>(z, ecs, ees, cnt, basep, rowlist, scal,
                                              out + O_ECS, out + O_EES, out + O_EMB, out + O_LOSS);
}

// Round 9
// 462.274 us; speedup vs baseline: 1.0650x; 1.0650x over previous
//
#include <hip/hip_runtime.h>
#include <hip/hip_bf16.h>

// Problem constants
#define NROWS 16384      // B*C = 32*512
#define DDIM  256        // H*W
#define KEMB  8192
#define DECAYF 0.99f
#define ONE_MINUS_DECAY 0.01f
#define EPSF 1e-5f

// Output layout (all float32, concatenated in return order)
#define O_QST   0
#define O_LOSS  4194304
#define O_IDX   4194305
#define O_EMB   4210689
#define O_ECS   6307841
#define O_EES   6316033

typedef __attribute__((ext_vector_type(8))) short short8;
typedef __attribute__((ext_vector_type(4))) float f32x4;

// fp32 -> bf16 (RNE) as raw ushort, and back
static __device__ __forceinline__ unsigned short f2bf(float x) {
    unsigned int u = __float_as_uint(x);
    return (unsigned short)((u + 0x7fffu + ((u >> 16) & 1u)) >> 16);
}
static __device__ __forceinline__ float bf2f(unsigned short h) {
    return __uint_as_float(((unsigned int)h) << 16);
}

// async global->LDS, 16B per lane; lds base wave-uniform, lane i lands at +16*i
static __device__ __forceinline__ void gload16(const unsigned short* g, unsigned short* l) {
    __builtin_amdgcn_global_load_lds(
        (const __attribute__((address_space(1))) unsigned int*)g,
        (__attribute__((address_space(3))) unsigned int*)l, 16, 0, 0);
}

// ---------------- prep_e: one wave per code k (R7-exact) ----------------
__global__ __launch_bounds__(256) void prep_e(const float* __restrict__ emb,
                                              const float* __restrict__ ecs_in,
                                              const float* __restrict__ ees_in,
                                              float* __restrict__ enorm,
                                              unsigned short* __restrict__ eh,
                                              unsigned short* __restrict__ el,
                                              float* __restrict__ o_ecs,
                                              float* __restrict__ o_ees,
                                              float* __restrict__ scal) {
    const int w = threadIdx.x >> 6;
    const int k = blockIdx.x * 4 + w;
    const int lane = threadIdx.x & 63;
    const int base = k * DDIM + lane * 4;
    const float4 v = *(const float4*)&emb[base];
    ushort4 h, l;
    {
        const float* vp = (const float*)&v;
        unsigned short hh;
        hh = f2bf(vp[0]); h.x = hh; l.x = f2bf(vp[0] - bf2f(hh));
        hh = f2bf(vp[1]); h.y = hh; l.y = f2bf(vp[1] - bf2f(hh));
        hh = f2bf(vp[2]); h.z = hh; l.z = f2bf(vp[2] - bf2f(hh));
        hh = f2bf(vp[3]); h.w = hh; l.w = f2bf(vp[3] - bf2f(hh));
    }
    *(ushort4*)&eh[base] = h;
    *(ushort4*)&el[base] = l;
    const float4 s = *(const float4*)&ees_in[base];
    float4 so;
    so.x = DECAYF * s.x; so.y = DECAYF * s.y; so.z = DECAYF * s.z; so.w = DECAYF * s.w;
    *(float4*)&o_ees[base] = so;
    float sum = v.x * v.x + v.y * v.y + v.z * v.z + v.w * v.w;
    for (int o = 32; o; o >>= 1) sum += __shfl_down(sum, o);
    __shared__ float sc[4];
    if (lane == 0) {
        enorm[k] = sum;
        const float c = DECAYF * ecs_in[k];
        o_ecs[k] = c;
        sc[w] = c;
    }
    __syncthreads();
    if (threadIdx.x == 0) atomicAdd(&scal[1], sc[0] + sc[1] + sc[2] + sc[3]);
}

// ---------------- prep_z: one wave per row (R7-exact) ----------------
__global__ __launch_bounds__(256) void prep_z(const float* __restrict__ z,
                                              unsigned short* __restrict__ zh,
                                              unsigned short* __restrict__ zl,
                                              unsigned long long* __restrict__ key64) {
    const int n = blockIdx.x * 4 + (threadIdx.x >> 6);
    const int lane = threadIdx.x & 63;
    const int base = n * DDIM + lane * 4;
    const float4 v = *(const float4*)&z[base];
    ushort4 h, l;
    {
        const float* vp = (const float*)&v;
        unsigned short hh;
        hh = f2bf(vp[0]); h.x = hh; l.x = f2bf(vp[0] - bf2f(hh));
        hh = f2bf(vp[1]); h.y = hh; l.y = f2bf(vp[1] - bf2f(hh));
        hh = f2bf(vp[2]); h.z = hh; l.z = f2bf(vp[2] - bf2f(hh));
        hh = f2bf(vp[3]); h.w = hh; l.w = f2bf(vp[3] - bf2f(hh));
    }
    *(ushort4*)&zh[base] = h;
    *(ushort4*)&zl[base] = l;
    if (lane == 0) key64[n] = ~0ull;
}

// ---------------- argmin_mfma: dbuf single-barrier bf16x3 GEMM + argmin -----
// Block 128x128, 4 waves (2x2 of 64x64), BK=32. Double-buffered LDS (64 KB,
// 2 blocks/CU): one __syncthreads per K-step; prefetch of step k+1 issued
// right after the barrier and consumed only at the NEXT barrier, so the
// vmcnt(0) drain overlaps the whole compute phase. 1-D grid with XCD-aware
// swizzle: xcd=L&7 owns a 16-row-tile z-slice (2 MB, L2-resident), sweeps
// col-tiles outer / rows inner (each 128KB e col-tile L2-reused 16x).
__global__ __launch_bounds__(256) void argmin_mfma(const unsigned short* __restrict__ zh,
                                                   const unsigned short* __restrict__ zl,
                                                   const unsigned short* __restrict__ eh,
                                                   const unsigned short* __restrict__ el,
                                                   const float* __restrict__ enorm,
                                                   unsigned long long* __restrict__ key64) {
    __shared__ unsigned short Ah[2][128][32];
    __shared__ unsigned short Al[2][128][32];
    __shared__ unsigned short Bh[2][128][32];
    __shared__ unsigned short Bl[2][128][32];

    const int tid = threadIdx.x;
    const int lane = tid & 63;
    const int wid = tid >> 6;
    const int wm = wid >> 1, wn = wid & 1;
    const int tx = lane & 15, quad = lane >> 4;

    // XCD swizzle (performance heuristic only; correctness mapping-independent)
    const int L = (int)blockIdx.x;
    const int xcd = L & 7;
    const int s = L >> 3;                    // 0..1023
    const int row0 = (xcd * 16 + (s & 15)) * 128;
    const int col0 = (s >> 4) * 128;

    const int w32 = wid * 32;
    const int r16 = lane >> 2;
    const int c8 = (lane & 3) * 8;

    f32x4 acc[4][4];
#pragma unroll
    for (int i = 0; i < 4; i++)
#pragma unroll
        for (int j = 0; j < 4; j++) acc[i][j] = (f32x4){0.f, 0.f, 0.f, 0.f};

    // prologue: stage step 0 into buffer 0
#pragma unroll
    for (int i = 0; i < 2; i++) {
        const int lr = w32 + i * 16;
        const size_t ga = (size_t)(row0 + lr + r16) * DDIM + c8;
        const size_t gb = (size_t)(col0 + lr + r16) * DDIM + c8;
        gload16(&zh[ga], &Ah[0][lr][0]);
        gload16(&zl[ga], &Al[0][lr][0]);
        gload16(&eh[gb], &Bh[0][lr][0]);
        gload16(&el[gb], &Bl[0][lr][0]);
    }

    for (int step = 0; step < 8; ++step) {
        const int cur = step & 1;
        __syncthreads();   // buf[cur] staging complete; prev frag reads done
        if (step < 7) {    // prefetch next tile into the other buffer
            const int nb = cur ^ 1;
            const int dstep = (step + 1) * 32;
#pragma unroll
            for (int i = 0; i < 2; i++) {
                const int lr = w32 + i * 16;
                const size_t ga = (size_t)(row0 + lr + r16) * DDIM + dstep + c8;
                const size_t gb = (size_t)(col0 + lr + r16) * DDIM + dstep + c8;
                gload16(&zh[ga], &Ah[nb][lr][0]);
                gload16(&zl[ga], &Al[nb][lr][0]);
                gload16(&eh[gb], &Bh[nb][lr][0]);
                gload16(&el[gb], &Bl[nb][lr][0]);
            }
        }

        short8 aH[4], aL[4], bH[4], bL[4];
        const int ar = wm * 64 + tx;
        const int br = wn * 64 + tx;
#pragma unroll
        for (int mi = 0; mi < 4; mi++) {
            aH[mi] = *(const short8*)&Ah[cur][ar + mi * 16][quad * 8];
            aL[mi] = *(const short8*)&Al[cur][ar + mi * 16][quad * 8];
        }
#pragma unroll
        for (int nj = 0; nj < 4; nj++) {
            bH[nj] = *(const short8*)&Bh[cur][br + nj * 16][quad * 8];
            bL[nj] = *(const short8*)&Bl[cur][br + nj * 16][quad * 8];
        }
#pragma unroll
        for (int mi = 0; mi < 4; mi++)
#pragma unroll
            for (int nj = 0; nj < 4; nj++) {
                acc[mi][nj] = __builtin_amdgcn_mfma_f32_16x16x32_bf16(aH[mi], bH[nj], acc[mi][nj], 0, 0, 0);
                acc[mi][nj] = __builtin_amdgcn_mfma_f32_16x16x32_bf16(aL[mi], bH[nj], acc[mi][nj], 0, 0, 0);
                acc[mi][nj] = __builtin_amdgcn_mfma_f32_16x16x32_bf16(aH[mi], bL[nj], acc[mi][nj], 0, 0, 0);
            }
    }

    // epilogue: dist = ||e||^2 - 2 x.e ; fused argmin, k-ascending tie-break.
    // C/D layout: col = lane&15 (+nj*16), row = quad*4 + reg (+mi*16)
    float en[4];
    int colv[4];
#pragma unroll
    for (int nj = 0; nj < 4; nj++) {
        colv[nj] = col0 + wn * 64 + nj * 16 + tx;
        en[nj] = enorm[colv[nj]];
    }
#pragma unroll
    for (int mi = 0; mi < 4; mi++) {
#pragma unroll
        for (int r = 0; r < 4; r++) {
            unsigned long long best = ~0ull;
#pragma unroll
            for (int nj = 0; nj < 4; nj++) {
                float d = en[nj] - 2.0f * acc[mi][nj][r];
                unsigned int db = __float_as_uint(d);
                db = (db & 0x80000000u) ? ~db : (db | 0x80000000u);
                unsigned long long key = ((unsigned long long)db << 32) | (unsigned int)colv[nj];
                if (key < best) best = key;
            }
#pragma unroll
            for (int m = 1; m < 16; m <<= 1) {
                unsigned long long o = __shfl_xor(best, m);
                if (o < best) best = o;
            }
            if (tx == 0)
                atomicMin(&key64[row0 + wm * 64 + mi * 16 + quad * 4 + r], best);
        }
    }
}

// ---------------- quant_stats: 4 rows per wave, block-reduced loss (R7) -----
__global__ __launch_bounds__(256) void quant_stats(const float* __restrict__ z,
                                                   const float* __restrict__ emb,
                                                   const unsigned long long* __restrict__ key64,
                                                   float* __restrict__ o_qst,
                                                   float* __restrict__ o_idx,
                                                   float* __restrict__ o_ecs,
                                                   float* __restrict__ o_ees,
                                                   float* __restrict__ scal) {
    const int w = threadIdx.x >> 6;
    const int lane = threadIdx.x & 63;
    const int nbase = blockIdx.x * 16 + w * 4;
    const int d0 = lane * 4;
    float ploc = 0.f;
#pragma unroll
    for (int r = 0; r < 4; r++) {
        const int n = nbase + r;
        const int k = (int)(key64[n] & 0xFFFFFFFFull);
        const float4 zv = *(const float4*)&z[n * DDIM + d0];
        const float4 ev = *(const float4*)&emb[k * DDIM + d0];
        const float dx = ev.x - zv.x, dy = ev.y - zv.y, dz2 = ev.z - zv.z, dw = ev.w - zv.w;
        float4 q;
        q.x = zv.x + dx; q.y = zv.y + dy; q.z = zv.z + dz2; q.w = zv.w + dw;
        *(float4*)&o_qst[n * DDIM + d0] = q;
        ploc += dx * dx + dy * dy + dz2 * dz2 + dw * dw;
        if (lane == 0) {
            o_idx[n] = (float)k;
            atomicAdd(&o_ecs[k], ONE_MINUS_DECAY);
        }
        atomicAdd(&o_ees[k * DDIM + d0 + 0], ONE_MINUS_DECAY * zv.x);
        atomicAdd(&o_ees[k * DDIM + d0 + 1], ONE_MINUS_DECAY * zv.y);
        atomicAdd(&o_ees[k * DDIM + d0 + 2], ONE_MINUS_DECAY * zv.z);
        atomicAdd(&o_ees[k * DDIM + d0 + 3], ONE_MINUS_DECAY * zv.w);
    }
    for (int o = 32; o; o >>= 1) ploc += __shfl_down(ploc, o);
    __shared__ float sh[4];
    if (lane == 0) sh[w] = ploc;
    __syncthreads();
    if (threadIdx.x == 0) atomicAdd(&scal[0], sh[0] + sh[1] + sh[2] + sh[3]);
}

// ---------------- finalize: new_embedding + loss scalar (R7) ----------------
__global__ __launch_bounds__(256) void finalize_kernel(const float* __restrict__ o_ecs,
                                                       const float* __restrict__ o_ees,
                                                       const float* __restrict__ scal,
                                                       float* __restrict__ o_emb,
                                                       float* __restrict__ o_loss) {
    const int k = blockIdx.x;
    const int d = threadIdx.x;
    const float ntot = scal[1] + ONE_MINUS_DECAY * (float)NROWS;
    const float ecs = o_ecs[k];
    const float sm = (ecs + EPSF) / (ntot + (float)KEMB * EPSF) * ntot;
    o_emb[k * DDIM + d] = o_ees[k * DDIM + d] / sm;
    if (k == 0 && d == 0) o_loss[0] = 0.25f * scal[0] / (float)(NROWS * DDIM);
}

extern "C" void kernel_launch(void* const* d_in, const int* in_sizes, int n_in,
                              void* d_out, int out_size, void* d_ws, size_t ws_size,
                              hipStream_t stream) {
    const float* z   = (const float*)d_in[0];
    const float* emb = (const float*)d_in[1];
    const float* ecs = (const float*)d_in[2];
    const float* ees = (const float*)d_in[3];

    float* out = (float*)d_out;
    char*  ws  = (char*)d_ws;

    // small scratch at head of ws: norms (32KB), key64 (128KB), scal (8B)
    float* enorm = (float*)ws;                                    // 8192 f
    unsigned long long* key64 = (unsigned long long*)(ws + 32768);// 16384 u64
    float* scal = (float*)(ws + 163840);

    // bf16 hi/lo scratch: prefer d_ws if large enough, else alias output
    // regions overwritten later (zh/zl in O_QST, eh/el in O_EMB).
    const size_t big0 = 164096;
    const size_t bigbytes = (size_t)(NROWS + KEMB) * DDIM * 2 * 2;// 24 MB
    unsigned short *zh, *zl, *ehp, *elp;
    if (ws_size >= big0 + bigbytes) {
        zh  = (unsigned short*)(ws + big0);
        zl  = zh + NROWS * DDIM;
        ehp = zl + NROWS * DDIM;
        elp = ehp + KEMB * DDIM;
    } else {
        zh  = (unsigned short*)(out + O_QST);
        zl  = zh + NROWS * DDIM;
        ehp = (unsigned short*)(out + O_EMB);
        elp = ehp + KEMB * DDIM;
    }

    hipMemsetAsync(scal, 0, 2 * sizeof(float), stream);
    prep_e<<<KEMB / 4, 256, 0, stream>>>(emb, ecs, ees, enorm, ehp, elp,
                                         out + O_ECS, out + O_EES, scal);
    prep_z<<<NROWS / 4, 256, 0, stream>>>(z, zh, zl, key64);
    argmin_mfma<<<(NROWS / 128) * (KEMB / 128), 256, 0, stream>>>(zh, zl, ehp, elp, enorm, key64);
    quant_stats<<<NROWS / 16, 256, 0, stream>>>(z, emb, key64, out + O_QST, out + O_IDX,
                                                out + O_ECS, out + O_EES, scal);
    finalize_kernel<<<KEMB, DDIM, 0, stream>>>(out + O_ECS, out + O_EES, scal,
                                               out + O_EMB, out + O_LOSS);
}